// Round 5
// baseline (271.319 us; speedup 1.0000x reference)
//
#include <hip/hip_runtime.h>

// Problem constants (from reference setup_inputs)
#define Bq 2
#define Cq 2
#define Dq 128
#define Hq 224
#define Wq 224
#define HWq (Hq * Wq)          // 50176 floats = 200 KB per z-plane
#define DHWq (Dq * HWq)        // 6422528
#define CDHWq (Cq * DHWq)      // 12845056
#define NT 1024                // threads per block
#define PER_T (HWq / NT)       // 49 pixels per thread

// v6: no-LDS, plane-linear gather restructure.
//
// Evidence trail (v1..v5): traffic is near-exact (223 vs 257 MB demand) and
// achieved BW scales with contiguous run length: 128B->2.0, 448B->2.6,
// 896B->3.1 TB/s, while time stays pinned ~86-90us (bytes x BW cancels).
// Every LDS-staged variant is stuck with z-strided HBM reads (200KB stride)
// because a block owning a w-column must walk 128 planes. nt-store retention
// lever: falsified (FETCH bit-identical v4 vs v5).
//
// v6 structure: block = (b,c,z). src reuse is only 2x (plane z feeds ~2 out
// planes) -> let L2/L3 capture it instead of LDS:
//  - flow plane read linearly (200 KB sequential)
//  - src gathered at per-lane z0 = clamp(z+flow): z0 spans z +/- ~8, so src
//    planes are demanded in near-linear z order (blockIdx ordered z-major),
//    each HBM line fetched once and reused by neighboring z-blocks via L2/L3.
//    Lanes with equal z0 are w-contiguous -> gather splits into few runs.
//  - out plane written linearly (nt stores, no reuse).
// No barriers, no LDS, low VGPR -> 32 waves/CU; dependent flow->gather chain
// hidden by TLP.
__global__ __launch_bounds__(NT, 2) void st_zwarp_v6_kernel(
    const float* __restrict__ src, const float* __restrict__ flow,
    float* __restrict__ out)
{
    const int tid = threadIdx.x;
    int blk = blockIdx.x;
    const int c = blk & 1;           blk >>= 1;   // c innermost: c=0/c=1 of
    const int z = blk & (Dq - 1);    blk >>= 7;   // same z run together and
    const int b = blk;                            // share flow reads in cache

    const float* src_bc  = src  + b * CDHWq + c * DHWq;       // plane base
    const float* flow_bz = flow + b * DHWq  + z * HWq;
    float*       out_bcz = out  + b * CDHWq + c * DHWq + z * HWq;

    const float zf_self = (float)z;

#pragma unroll 7
    for (int j = 0; j < PER_T; ++j) {
        const int hw = tid + j * NT;              // lane-linear in the plane
        const float fl = flow_bz[hw];
        float zc = fminf(fmaxf(zf_self + fl, 0.0f), (float)(Dq - 1));
        const float zfl = floorf(zc);
        const int z0 = (int)zfl;
        const float wz = zc - zfl;
        const int z1 = min(z0 + 1, Dq - 1);
        const float s0 = src_bc[z0 * HWq + hw];   // gather: per-lane z0,
        const float s1 = src_bc[z1 * HWq + hw];   // w-contiguous within z0
        __builtin_nontemporal_store(s0 + (s1 - s0) * wz, &out_bcz[hw]);
    }
}

extern "C" void kernel_launch(void* const* d_in, const int* in_sizes, int n_in,
                              void* d_out, int out_size, void* d_ws, size_t ws_size,
                              hipStream_t stream) {
    const float* src  = (const float*)d_in[0];
    const float* flow = (const float*)d_in[1];
    float* out = (float*)d_out;

    const int grid = Bq * Dq * Cq;   // 512 blocks = (b, z, c), c innermost
    st_zwarp_v6_kernel<<<grid, NT, 0, stream>>>(src, flow, out);
}

// Round 6
// 226.387 us; speedup vs baseline: 1.1985x; 1.1985x over previous
//
#include <hip/hip_runtime.h>

// Problem constants (from reference setup_inputs)
#define Bq 2
#define Cq 2
#define Dq 128
#define Hq 224
#define Wq 224
#define HWq (Hq * Wq)          // 50176
#define DHWq (Dq * HWq)        // 6422528
#define CDHWq (Cq * DHWq)      // 12845056
#define WT 112                 // w-tile (448B contiguous runs, 7 x 64B lines)
#define NWT (Wq / WT)          // 2
#define NT 512                 // threads per block
#define SLAB (Dq * WT)         // 14336 floats = 56 KB per (c) slab
#define NV4 (SLAB / 4 / NT)    // 7 staging insts per thread per c
#define PER_T (SLAB / NT)      // 28 compute elements per thread per c

typedef __attribute__((address_space(3))) void lds_void;
typedef const __attribute__((address_space(1))) void gbl_void;

// v7: all surviving levers on the v4 base.
//
// Evidence trail:
//  - v6: per-pixel global gather = address-divergence-bound (64 planes/wave
//    inst). LDS staging is structurally required.  [dead lever: gather]
//  - v5: nt stores changed nothing (FETCH bit-identical). [dead lever: LLC hints]
//  - v2: occupancy 34->61% changed nothing.       [dead lever: occupancy]
//  - v3 re-diagnosed: its 2.3x write blowup matches SCRATCH SPILLS (fl[28]
//    at a hard 64-VGPR cap), not L3 thrash. Its structure (flow-once in
//    regs, phase-separated compute=LDS+store-only) hit 3.1 TB/s. Reuse it,
//    spill-free.
//
// v7 = block (b,h,wt=112): stage BOTH c (112 KB LDS) so flow is read once
// (demand fetch 205->154 MB); flow preloaded to 28 regs pre-barrier; c=1
// staged async (global_load_lds into s[1]) while c=0 computes; compute
// phases are pure LDS+store. 512 thr, launch_bounds(512,2) -> 256-VGPR
// ceiling, no spill (v3's killer).
__global__ __launch_bounds__(NT, 2) void st_zwarp_v7_kernel(
    const float* __restrict__ src, const float* __restrict__ flow,
    float* __restrict__ out)
{
    __shared__ float s[Cq][SLAB];   // 112 KB: s[c][z*112 + w]

    const int tid = threadIdx.x;
    int blk = blockIdx.x;
    const int wt = blk & (NWT - 1);  blk >>= 1;   // NWT == 2
    const int h  = blk % Hq;
    const int b  = blk / Hq;

    const float* src_s  = src  + b * CDHWq + h * Wq + wt * WT;
    const float* flow_s = flow + b * DHWq  + h * Wq + wt * WT;
    float*       out_s  = out  + b * CDHWq + h * Wq + wt * WT;

    // ---- stage c=0 slab -> s[0] via direct DMA (448B runs, 64B-aligned)
#pragma unroll
    for (int k = 0; k < NV4; ++k) {
        const int i4 = tid + k * NT;
        const int z = i4 / (WT / 4);            // i4 / 28
        const int w = (i4 - z * (WT / 4)) * 4;
        __builtin_amdgcn_global_load_lds(
            (gbl_void*)(src_s + z * HWq + w),
            (lds_void*)(&s[0][z * WT + w]), 16, 0, 0);
    }

    // ---- flow -> 28 regs (in flight during the same drain; read ONCE,
    // reused for both c). 512 threads -> no spill at <=256 VGPR budget.
    float fl[PER_T];
#pragma unroll
    for (int j = 0; j < PER_T; ++j) {
        const int o = tid + j * NT;
        const int z = o / WT;
        const int w = o - z * WT;
        fl[j] = flow_s[z * HWq + w];
    }

    __syncthreads();   // drains vmcnt(0): s[0] + fl ready

    // ---- issue c=1 stage NOW (async into s[1]); it flies during c0 compute
#pragma unroll
    for (int k = 0; k < NV4; ++k) {
        const int i4 = tid + k * NT;
        const int z = i4 / (WT / 4);
        const int w = (i4 - z * (WT / 4)) * 4;
        __builtin_amdgcn_global_load_lds(
            (gbl_void*)(src_s + DHWq + z * HWq + w),
            (lds_void*)(&s[1][z * WT + w]), 16, 0, 0);
    }

    // ---- compute c=0: pure LDS + VALU + store (no global reads)
#pragma unroll
    for (int j = 0; j < PER_T; ++j) {
        const int o = tid + j * NT;
        const int z = o / WT;
        const int w = o - z * WT;
        float zc = fminf(fmaxf((float)z + fl[j], 0.0f), (float)(Dq - 1));
        const float zf = floorf(zc);
        const int z0 = (int)zf;
        const float wz = zc - zf;
        const int z1 = min(z0 + 1, Dq - 1);
        const float s0 = s[0][z0 * WT + w];
        const float s1 = s[0][z1 * WT + w];
        out_s[z * HWq + w] = s0 + (s1 - s0) * wz;
    }

    __syncthreads();   // drains vmcnt(0): s[1] ready

    // ---- compute c=1 (flow regs reused)
#pragma unroll
    for (int j = 0; j < PER_T; ++j) {
        const int o = tid + j * NT;
        const int z = o / WT;
        const int w = o - z * WT;
        float zc = fminf(fmaxf((float)z + fl[j], 0.0f), (float)(Dq - 1));
        const float zf = floorf(zc);
        const int z0 = (int)zf;
        const float wz = zc - zf;
        const int z1 = min(z0 + 1, Dq - 1);
        const float s0 = s[1][z0 * WT + w];
        const float s1 = s[1][z1 * WT + w];
        out_s[DHWq + z * HWq + w] = s0 + (s1 - s0) * wz;
    }
}

extern "C" void kernel_launch(void* const* d_in, const int* in_sizes, int n_in,
                              void* d_out, int out_size, void* d_ws, size_t ws_size,
                              hipStream_t stream) {
    const float* src  = (const float*)d_in[0];
    const float* flow = (const float*)d_in[1];
    float* out = (float*)d_out;

    const int grid = Bq * Hq * NWT;   // 896 blocks = (b, h, wt)
    st_zwarp_v7_kernel<<<grid, NT, 0, stream>>>(src, flow, out);
}